// Round 8
// baseline (183.488 us; speedup 1.0000x reference)
//
#include <hip/hip_runtime.h>
#include <stdint.h>

#define PRIME 1000003u
#define NORD  1000002u
#define KCH   16
#define BATCH 4
#define NPATCH 784
#define LLEN  9
#define IPMAX 9000          // |<x,y>| <= 20*50*9
#define TBLN  (2*IPMAX+1)
#define NDEC  (KCH*BATCH*NPATCH)   // 50176

// Barrett: M = floor(2^41/p) = 2199016; exact for t < 2^40 with one cond-sub.
__device__ __forceinline__ uint32_t mmul(uint32_t a, uint32_t b) {
    uint64_t t = (uint64_t)a * (uint64_t)b;
    uint32_t q = (uint32_t)((t * 2199016ull) >> 41);
    uint32_t r = (uint32_t)t - q * PRIME;
    return (r >= PRIME) ? r - PRIME : r;
}

__device__ __forceinline__ uint32_t mpow(uint32_t base, uint32_t exp) {
    uint32_t r = 1u, b = base;
    while (exp) {
        if (exp & 1u) r = mmul(r, b);
        b = mmul(b, b);
        exp >>= 1;
    }
    return r;
}

// ---------------- Kernel 1: dlog lookup table -------------------------------
// table[g^e mod p] = e for e in [-9000,9000]. Only queried entries are ever
// written (decrypted values are guaranteed g^e, |e|<=9000), so ws poison
// elsewhere is never read.
__global__ void build_table(const int* __restrict__ g_in, int* __restrict__ table) {
    int e = blockIdx.x * blockDim.x + threadIdx.x;
    if (e >= TBLN) return;
    int es = e - IPMAX;
    uint32_t exp = (es >= 0) ? (uint32_t)es : (uint32_t)(es + (int)NORD);
    table[mpow((uint32_t)g_in[0], exp)] = es;
}

// ---------------- Kernel 2: IPFE decrypt + table dlog + bias1+bn1+relu ------
// featr: [B][16][28][28] post bn1+relu. 196 blocks x 256 threads.
__global__ void __launch_bounds__(256) decrypt(
    const int* __restrict__ ct0, const int* __restrict__ cts,
    const int* __restrict__ y, const int* __restrict__ sk_y,
    const float* __restrict__ bias1,
    const float* __restrict__ bn1_g, const float* __restrict__ bn1_b,
    const float* __restrict__ bn1_m, const float* __restrict__ bn1_v,
    const int* __restrict__ table, float* __restrict__ featr) {
    int gtid = blockIdx.x * 256 + threadIdx.x;
    if (gtid >= NDEC) return;
    // 3136 = 49 full waves per k -> k is wave-uniform; force scalarization.
    int k = __builtin_amdgcn_readfirstlane(gtid / (BATCH * NPATCH));
    int r = gtid % (BATCH * NPATCH);
    int b = r / NPATCH;
    int j = r % NPATCH;

    const int* crow = cts + ((b * NPATCH) + j) * LLEN;
    const int* yrow = y + k * LLEN;

    uint32_t num_p = 1u, num_n = 1u;
#pragma unroll
    for (int i = 0; i < LLEN; i++) {
        int yi = yrow[i];                  // scalar load; uniform branch
        uint32_t c = (uint32_t)crow[i];
        if (yi > 0)       num_p = mmul(num_p, mpow(c, (uint32_t)yi));
        else if (yi < 0)  num_n = mmul(num_n, mpow(c, (uint32_t)(-yi)));
    }
    uint32_t den = mpow((uint32_t)ct0[b * NPATCH + j], (uint32_t)sk_y[k]);
    den = mmul(den, num_n);
    uint32_t val = mmul(num_p, mpow(den, PRIME - 2u));  // const exp: unrolls

    int ip = table[val];                   // guaranteed hit, |ip|<=9000

    float sc = bn1_g[k] * rsqrtf(bn1_v[k] + 1e-5f);
    float shf = (bias1[k] - bn1_m[k]) * sc + bn1_b[k];
    float v_ = fmaf((float)ip, sc * 1e-4f, shf);
    featr[((b * KCH) + k) * NPATCH + j] = fmaxf(v_, 0.0f);
}

// ---------------- Kernel 3: pool(28->14) + conv2 + bn2 + relu + pool(14->7) -
// block = (b, oc): 128 blocks x 256 threads. s2g: [B][32][7][7]
__global__ void __launch_bounds__(256) conv2_k(
    const float* __restrict__ featr,
    const float* __restrict__ conv2_w, const float* __restrict__ conv2_b,
    const float* __restrict__ bn2_g, const float* __restrict__ bn2_b,
    const float* __restrict__ bn2_m, const float* __restrict__ bn2_v,
    float* __restrict__ s2g) {
    const int b  = blockIdx.x >> 5;
    const int oc = blockIdx.x & 31;
    const int tid = threadIdx.x;

    __shared__ float s1p[16][16][16];   // padded halo of zeros, 16 KB
    __shared__ float w[16 * 9];
    __shared__ float co[196];

    for (int i = tid; i < 16 * 16 * 16; i += 256)
        ((float*)s1p)[i] = 0.0f;
    if (tid < 144) w[tid] = conv2_w[oc * 144 + tid];
    __syncthreads();
    for (int i = tid; i < 16 * 196; i += 256) {
        int ic = i / 196, pos = i % 196;
        int yy = pos / 14, xx = pos % 14;
        const float* fp = featr + ((b * 16 + ic) * 784) + (2 * yy) * 28 + 2 * xx;
        s1p[ic][yy + 1][xx + 1] = fmaxf(fmaxf(fp[0], fp[1]), fmaxf(fp[28], fp[29]));
    }
    __syncthreads();

    if (tid < 196) {
        int oh = tid / 14, ow = tid % 14;
        float a0 = 0.0f, a1 = 0.0f, a2 = 0.0f;
#pragma unroll
        for (int ic = 0; ic < 16; ic++) {
            const float* wp = &w[ic * 9];
            const float* sp = &s1p[ic][oh][ow];
            a0 = fmaf(sp[0],  wp[0], fmaf(sp[1],  wp[1], fmaf(sp[2],  wp[2], a0)));
            a1 = fmaf(sp[16], wp[3], fmaf(sp[17], wp[4], fmaf(sp[18], wp[5], a1)));
            a2 = fmaf(sp[32], wp[6], fmaf(sp[33], wp[7], fmaf(sp[34], wp[8], a2)));
        }
        float sc = bn2_g[oc] * rsqrtf(bn2_v[oc] + 1e-5f);
        float shf = bn2_b[oc] - bn2_m[oc] * sc;
        co[tid] = fmaxf((a0 + a1 + a2 + conv2_b[oc]) * sc + shf, 0.0f);
    }
    __syncthreads();

    if (tid < 49) {
        int oh = tid / 7, ow = tid % 7;
        const float* c0 = &co[(2 * oh) * 14 + 2 * ow];
        s2g[((b * 32 + oc) * 49) + tid] =
            fmaxf(fmaxf(c0[0], c0[1]), fmaxf(c0[14], c0[15]));
    }
}

// ---------------- Kernel 4: conv3+bn3+relu+pool(7->3)+fc1+relu+fc2 ----------
// 4 blocks (one per sample) x 1024 threads (16 waves). Wave w owns conv3
// output channels 4w..4w+3 (oc wave-uniform -> scalar weight loads); s2 tile
// staged ONCE per block (vs 64x in the split version); fc1 wave-coalesced.
__global__ void __launch_bounds__(1024) conv3fc_k(
    const float* __restrict__ s2g,
    const float* __restrict__ conv3_w, const float* __restrict__ conv3_b,
    const float* __restrict__ bn3_g, const float* __restrict__ bn3_b,
    const float* __restrict__ bn3_m, const float* __restrict__ bn3_v,
    const float* __restrict__ fc1_w, const float* __restrict__ fc1_b,
    const float* __restrict__ fc2_w, const float* __restrict__ fc2_b,
    float* __restrict__ out) {
    const int b = blockIdx.x;
    const int tid = threadIdx.x;
    const int wid = tid >> 6, lane = tid & 63;

    __shared__ float s2p[32][9][9];    // padded halo, 10.4 KB
    __shared__ float co[64][49];       // conv3 post-bn-relu, 12.25 KB
    __shared__ float s3[576];          // pooled
    __shared__ float h[128];           // fc1 out

    for (int i = tid; i < 32 * 81; i += 1024)
        ((float*)s2p)[i] = 0.0f;
    __syncthreads();
    for (int i = tid; i < 32 * 49; i += 1024) {
        int ic = i / 49, pos = i % 49;
        s2p[ic][pos / 7 + 1][pos % 7 + 1] = s2g[((b * 32 + ic) * 49) + pos];
    }
    __syncthreads();

    // conv3: wave wid -> oc = 4*wid + oo; lane < 49 -> one output position
#pragma unroll
    for (int oo = 0; oo < 4; oo++) {
        int oc = wid * 4 + oo;                       // wave-uniform
        if (lane < 49) {
            int oh = lane / 7, ow = lane % 7;
            const float* wb = conv3_w + oc * 288;    // uniform base -> s_loads
            float a0 = 0.0f, a1 = 0.0f, a2 = 0.0f;
#pragma unroll
            for (int ic = 0; ic < 32; ic++) {
                const float* wp = wb + ic * 9;
                const float* sp = &s2p[ic][oh][ow];
                a0 = fmaf(sp[0],  wp[0], fmaf(sp[1],  wp[1], fmaf(sp[2],  wp[2], a0)));
                a1 = fmaf(sp[9],  wp[3], fmaf(sp[10], wp[4], fmaf(sp[11], wp[5], a1)));
                a2 = fmaf(sp[18], wp[6], fmaf(sp[19], wp[7], fmaf(sp[20], wp[8], a2)));
            }
            float sc = bn3_g[oc] * rsqrtf(bn3_v[oc] + 1e-5f);
            float shf = bn3_b[oc] - bn3_m[oc] * sc;
            co[oc][lane] = fmaxf((a0 + a1 + a2 + conv3_b[oc]) * sc + shf, 0.0f);
        }
    }
    __syncthreads();

    // pool 7->3 (windows at rows/cols {0,2,4}) -> s3 flat [64][3][3]
    if (tid < 576) {
        int oc = tid / 9, pp = tid % 9;
        int oh = pp / 3, ow = pp % 3;
        const float* c0 = &co[oc][(2 * oh) * 7 + 2 * ow];
        s3[tid] = fmaxf(fmaxf(c0[0], c0[1]), fmaxf(c0[7], c0[8]));
    }
    __syncthreads();

    // fc1: wave wid -> outputs 8*wid..8*wid+7, lanes across 576 (coalesced)
#pragma unroll
    for (int oo = 0; oo < 8; oo++) {
        int o = wid * 8 + oo;
        const float* w = fc1_w + o * 576;
        float acc = 0.0f;
#pragma unroll
        for (int jj = 0; jj < 9; jj++)
            acc = fmaf(s3[jj * 64 + lane], w[jj * 64 + lane], acc);
#pragma unroll
        for (int off = 32; off; off >>= 1) acc += __shfl_down(acc, off);
        if (lane == 0) h[o] = fmaxf(acc + fc1_b[o], 0.0f);
    }
    __syncthreads();

    // fc2: waves 0..9, one output each
    if (wid < 10) {
        const float* w = fc2_w + wid * 128;
        float acc = fmaf(h[lane], w[lane], 0.0f);
        acc = fmaf(h[64 + lane], w[64 + lane], acc);
#pragma unroll
        for (int off = 32; off; off >>= 1) acc += __shfl_down(acc, off);
        if (lane == 0) out[b * 10 + wid] = acc + fc2_b[wid];
    }
}

extern "C" void kernel_launch(void* const* d_in, const int* in_sizes, int n_in,
                              void* d_out, int out_size, void* d_ws, size_t ws_size,
                              hipStream_t stream) {
    const int*   ct0    = (const int*)d_in[0];
    const int*   cts    = (const int*)d_in[1];
    const int*   y      = (const int*)d_in[2];
    const int*   sk_y   = (const int*)d_in[3];
    const float* bias1  = (const float*)d_in[4];
    const float* bn1_g  = (const float*)d_in[5];
    const float* bn1_b  = (const float*)d_in[6];
    const float* bn1_m  = (const float*)d_in[7];
    const float* bn1_v  = (const float*)d_in[8];
    const float* conv2_w = (const float*)d_in[9];
    const float* conv2_b = (const float*)d_in[10];
    const float* bn2_g  = (const float*)d_in[11];
    const float* bn2_b  = (const float*)d_in[12];
    const float* bn2_m  = (const float*)d_in[13];
    const float* bn2_v  = (const float*)d_in[14];
    const float* conv3_w = (const float*)d_in[15];
    const float* conv3_b = (const float*)d_in[16];
    const float* bn3_g  = (const float*)d_in[17];
    const float* bn3_b  = (const float*)d_in[18];
    const float* bn3_m  = (const float*)d_in[19];
    const float* bn3_v  = (const float*)d_in[20];
    const float* fc1_w  = (const float*)d_in[21];
    const float* fc1_b  = (const float*)d_in[22];
    const float* fc2_w  = (const float*)d_in[23];
    const float* fc2_b  = (const float*)d_in[24];
    const int*   g_in   = (const int*)d_in[25];
    float* out = (float*)d_out;

    // Workspace layout (bytes):
    //   [0,        4000256)  int32 dlog table (p entries)
    //   [4000256,  4200960)  float featr [4][16][28][28]
    //   [4200960,  4226048)  float s2g   [4][32][7][7]
    char* ws = (char*)d_ws;
    int*   table = (int*)ws;
    float* featr = (float*)(ws + 4000256);
    float* s2g   = (float*)(ws + 4200960);

    build_table<<<(TBLN + 255) / 256, 256, 0, stream>>>(g_in, table);

    decrypt<<<NDEC / 256, 256, 0, stream>>>(
        ct0, cts, y, sk_y, bias1, bn1_g, bn1_b, bn1_m, bn1_v, table, featr);

    conv2_k<<<BATCH * 32, 256, 0, stream>>>(
        featr, conv2_w, conv2_b, bn2_g, bn2_b, bn2_m, bn2_v, s2g);

    conv3fc_k<<<BATCH, 1024, 0, stream>>>(
        s2g, conv3_w, conv3_b, bn3_g, bn3_b, bn3_m, bn3_v,
        fc1_w, fc1_b, fc2_w, fc2_b, out);
}